// Round 4
// baseline (44.818 us; speedup 1.0000x reference)
//
#include <hip/hip_runtime.h>

#define HH 512
#define WW 512
#define NB 4
#define RR 4
#define EPSF 1e-8f

// k_f1: 32x16 output tile; staged h-sums 13ch x 24rows x 32cols (39 KB -> 4 WG/CU)
#define F1_R 24
// k_f2: 64x16 output tile; staged A,b 24rows x 65(pad) float4 (25 KB)
#define F2_R 24
#define F2_WP 65

__device__ __forceinline__ float4 f4add(float4 a, float4 b) {
    return make_float4(a.x + b.x, a.y + b.y, a.z + b.z, a.w + b.w);
}
__device__ __forceinline__ float4 f4sub(float4 a, float4 b) {
    return make_float4(a.x - b.x, a.y - b.y, a.z - b.z, a.w - b.w);
}

// load 12-float horizontal window (3x aligned float4), zero-padded outside image
#define LOADW(W, P) { \
    float4 qa = vlo ? *(const float4*)((P) + gj0 - 4) : make_float4(0.f,0.f,0.f,0.f); \
    float4 qb =       *(const float4*)((P) + gj0); \
    float4 qc = vhi ? *(const float4*)((P) + gj0 + 4) : make_float4(0.f,0.f,0.f,0.f); \
    W[0]=qa.x; W[1]=qa.y; W[2]=qa.z;  W[3]=qa.w; \
    W[4]=qb.x; W[5]=qb.y; W[6]=qb.z;  W[7]=qb.w; \
    W[8]=qc.x; W[9]=qc.y; W[10]=qc.z; W[11]=qc.w; }

// horizontal box of 4 consecutive cols via sliding sums -> LDS
#define HBOXS(ch, EXPR) { \
    float p[12]; \
    _Pragma("unroll") for (int k = 0; k < 12; ++k) p[k] = (EXPR); \
    float t0 = ((p[0]+p[1])+(p[2]+p[3])) + ((p[4]+p[5])+(p[6]+p[7])) + p[8]; \
    float t1 = t0 - p[0] + p[9]; \
    float t2 = t1 - p[1] + p[10]; \
    float t3 = t2 - p[2] + p[11]; \
    *(float4*)&lds[ch][r][q4] = make_float4(t0, t1, t2, t3); }

// ============ Kernel F1: y,x -> A,b ============
__global__ __launch_bounds__(256, 4) void k_f1(const float* __restrict__ y,
                                               const float* __restrict__ x,
                                               float* __restrict__ ab) {
    __shared__ float lds[13][F1_R][32];
    const int bid = (int)blockIdx.x;
    // XCD slab swizzle: 2048 blocks, each XCD gets 256 consecutive work ids
    const int w   = ((bid & 7) << 8) | (bid >> 3);
    const int ti  = (w & 31) << 4;          // row-tile (fastest -> vertical locality)
    const int tj  = ((w >> 5) & 15) << 5;
    const int n   = w >> 9;
    const int tid = (int)threadIdx.x;

    const size_t plane = (size_t)HH * WW;
    const float* yp = y + (size_t)n * plane;
    const float* xp = x + (size_t)(3 * n) * plane;

    // ---- stage 1: h-sums of 13 product channels for 24 rows x 32 cols ----
    if (tid < F1_R * 8) {
        const int r   = tid >> 3;           // 0..23
        const int q4  = (tid & 7) << 2;     // 0..28
        const int gr  = ti - 4 + r;
        const int gj0 = tj + q4;
        if (gr >= 0 && gr < HH) {
            const float* yr = yp + (size_t)gr * WW;
            const float* ar = xp + (size_t)gr * WW;
            const float* br = ar + plane;
            const float* cr = br + plane;
            const bool vlo = gj0 >= 4;
            const bool vhi = gj0 < WW - 4;
            float aw[12], bw[12], cw[12], yw[12];
            LOADW(aw, ar); LOADW(bw, br); LOADW(cw, cr); LOADW(yw, yr);
            HBOXS(0,  aw[k]);
            HBOXS(1,  bw[k]);
            HBOXS(2,  cw[k]);
            HBOXS(3,  yw[k]);
            HBOXS(4,  yw[k] * aw[k]);
            HBOXS(5,  yw[k] * bw[k]);
            HBOXS(6,  yw[k] * cw[k]);
            HBOXS(7,  aw[k] * aw[k]);
            HBOXS(8,  aw[k] * bw[k]);
            HBOXS(9,  aw[k] * cw[k]);
            HBOXS(10, bw[k] * bw[k]);
            HBOXS(11, bw[k] * cw[k]);
            HBOXS(12, cw[k] * cw[k]);
        } else {
            const float4 z = make_float4(0.f, 0.f, 0.f, 0.f);
#pragma unroll
            for (int ch = 0; ch < 13; ++ch) *(float4*)&lds[ch][r][q4] = z;
        }
    }
    __syncthreads();

    // ---- stage 2: vertical 9-sum (sliding pair) + 3x3 solve, 2 rows/thread ----
    const int col = tid & 31;
    const int rg  = tid >> 5;               // 0..7
    const int r0  = rg << 1;

    float s0[13], s1[13];
#pragma unroll
    for (int ch = 0; ch < 13; ++ch) {
        float v[10];
#pragma unroll
        for (int k = 0; k < 10; ++k) v[k] = lds[ch][r0 + k][col];
        float t = ((v[0]+v[1])+(v[2]+v[3])) + ((v[4]+v[5])+(v[6]+v[7])) + v[8];
        s0[ch] = t;
        s1[ch] = t - v[0] + v[9];
    }

    const int gj  = tj + col;
    const int j0r = gj - RR < 0 ? 0 : gj - RR;
    const int j1r = gj + RR > WW - 1 ? WW - 1 : gj + RR;
    const float wcnt = (float)(j1r - j0r + 1);
    float4* abp = (float4*)ab + (size_t)n * plane;

#define SOLVE(S, I) { \
    const int i0r = (I) - RR < 0 ? 0 : (I) - RR; \
    const int i1r = (I) + RR > HH - 1 ? HH - 1 : (I) + RR; \
    const float invn = 1.0f / ((float)(i1r - i0r + 1) * wcnt); \
    float mx0 = S[0]*invn, mx1 = S[1]*invn, mx2 = S[2]*invn, my = S[3]*invn; \
    float cy0 = S[4]*invn - my*mx0; \
    float cy1 = S[5]*invn - my*mx1; \
    float cy2 = S[6]*invn - my*mx2; \
    float a00 = S[7]*invn  - mx0*mx0 + EPSF; \
    float a01 = S[8]*invn  - mx0*mx1; \
    float a02 = S[9]*invn  - mx0*mx2; \
    float a11 = S[10]*invn - mx1*mx1 + EPSF; \
    float a12 = S[11]*invn - mx1*mx2; \
    float a22 = S[12]*invn - mx2*mx2 + EPSF; \
    float c00 = a11*a22 - a12*a12; \
    float c01 = a02*a12 - a01*a22; \
    float c02 = a01*a12 - a02*a11; \
    float det = a00*c00 + a01*c01 + a02*c02; \
    float id  = 1.0f / det; \
    float i00 = c00*id, i01 = c01*id, i02 = c02*id; \
    float i11 = (a00*a22 - a02*a02)*id; \
    float i12 = (a01*a02 - a00*a12)*id; \
    float i22 = (a00*a11 - a01*a01)*id; \
    float A0 = cy0*i00 + cy1*i01 + cy2*i02; \
    float A1 = cy0*i01 + cy1*i11 + cy2*i12; \
    float A2 = cy0*i02 + cy1*i12 + cy2*i22; \
    float bb = my - (A0*mx0 + A1*mx1 + A2*mx2); \
    abp[(size_t)(I) * WW + gj] = make_float4(A0, A1, A2, bb); }

    SOLVE(s0, ti + r0);
    SOLVE(s1, ti + r0 + 1);
#undef SOLVE
}

// ============ Kernel F2: A,b,x -> out ============
__global__ __launch_bounds__(256, 4) void k_f2(const float* __restrict__ ab,
                                               const float* __restrict__ x,
                                               float* __restrict__ out) {
    __shared__ float4 lds[F2_R][F2_WP];     // padded stride: min-conflict b128 reads
    const int bid = (int)blockIdx.x;
    // XCD slab swizzle: 1024 blocks, 128 per XCD; same pixel->XCD map as k_f1
    const int w   = ((bid & 7) << 7) | (bid >> 3);
    const int ti  = (w & 31) << 4;
    const int tj  = ((w >> 5) & 7) << 6;
    const int n   = w >> 8;
    const int tid = (int)threadIdx.x;

    const size_t plane = (size_t)HH * WW;
    const float4* abp = (const float4*)ab + (size_t)n * plane;

    // ---- stage 1: h-box of interleaved A,b into LDS (24 rows x 64 cols) ----
    for (int task = tid; task < F2_R * 16; task += 256) {
        const int r   = task >> 4;
        const int q4  = (task & 15) << 2;
        const int gr  = ti - 4 + r;
        const int gj0 = tj + q4;
        const float4 z = make_float4(0.f, 0.f, 0.f, 0.f);
        if (gr >= 0 && gr < HH) {
            const float4* rr = abp + (size_t)gr * WW;
            const bool vlo = gj0 >= 4;
            const bool vhi = gj0 < WW - 4;
            float4 wv[12];
#pragma unroll
            for (int k = 0; k < 4; ++k) wv[k]     = vlo ? rr[gj0 - 4 + k] : z;
#pragma unroll
            for (int k = 0; k < 4; ++k) wv[4 + k] = rr[gj0 + k];
#pragma unroll
            for (int k = 0; k < 4; ++k) wv[8 + k] = vhi ? rr[gj0 + 4 + k] : z;

            float4 t0 = f4add(f4add(f4add(f4add(wv[0], wv[1]), f4add(wv[2], wv[3])),
                                    f4add(f4add(wv[4], wv[5]), f4add(wv[6], wv[7]))), wv[8]);
            float4 t1 = f4add(f4sub(t0, wv[0]), wv[9]);
            float4 t2 = f4add(f4sub(t1, wv[1]), wv[10]);
            float4 t3 = f4add(f4sub(t2, wv[2]), wv[11]);
            lds[r][q4 + 0] = t0;
            lds[r][q4 + 1] = t1;
            lds[r][q4 + 2] = t2;
            lds[r][q4 + 3] = t3;
        } else {
            lds[r][q4 + 0] = z; lds[r][q4 + 1] = z;
            lds[r][q4 + 2] = z; lds[r][q4 + 3] = z;
        }
    }
    __syncthreads();

    // ---- stage 2: vertical 9-sum + combine, one 4-col run per thread ----
    const int run = tid & 15;
    const int row = tid >> 4;               // 0..15
    const int q4  = run << 2;

    float4 a0 = lds[row][q4 + 0];
    float4 a1 = lds[row][q4 + 1];
    float4 a2 = lds[row][q4 + 2];
    float4 a3 = lds[row][q4 + 3];
#pragma unroll
    for (int k = 1; k < 9; ++k) {
        a0 = f4add(a0, lds[row + k][q4 + 0]);
        a1 = f4add(a1, lds[row + k][q4 + 1]);
        a2 = f4add(a2, lds[row + k][q4 + 2]);
        a3 = f4add(a3, lds[row + k][q4 + 3]);
    }

    const int i   = ti + row;
    const int i0r = i - RR < 0 ? 0 : i - RR;
    const int i1r = i + RR > HH - 1 ? HH - 1 : i + RR;
    const float ic = (float)(i1r - i0r + 1);

    const int gj0 = tj + q4;
    float wc[4];
#pragma unroll
    for (int k = 0; k < 4; ++k) {
        const int jc  = gj0 + k;
        const int j0r = jc - RR < 0 ? 0 : jc - RR;
        const int j1r = jc + RR > WW - 1 ? WW - 1 : jc + RR;
        wc[k] = 1.0f / (ic * (float)(j1r - j0r + 1));
    }

    const float* xp = x + (size_t)(3 * n) * plane;
    float* op = out + (size_t)n * plane;
    const size_t px = (size_t)i * WW + gj0;

    const float4 x0 = *(const float4*)(xp + px);
    const float4 x1 = *(const float4*)(xp + px + plane);
    const float4 x2 = *(const float4*)(xp + px + 2 * plane);

    float4 o;
    o.x = (a0.x * x0.x + a0.y * x1.x + a0.z * x2.x + a0.w) * wc[0];
    o.y = (a1.x * x0.y + a1.y * x1.y + a1.z * x2.y + a1.w) * wc[1];
    o.z = (a2.x * x0.z + a2.y * x1.z + a2.z * x2.z + a2.w) * wc[2];
    o.w = (a3.x * x0.w + a3.y * x1.w + a3.z * x2.w + a3.w) * wc[3];
    *(float4*)(op + px) = o;
}

extern "C" void kernel_launch(void* const* d_in, const int* in_sizes, int n_in,
                              void* d_out, int out_size, void* d_ws, size_t ws_size,
                              hipStream_t stream) {
    const float* y = (const float*)d_in[0];   // (4,1,512,512)
    const float* x = (const float*)d_in[1];   // (4,3,512,512)
    float* out = (float*)d_out;               // (4,1,512,512)

    float* ab = (float*)d_ws;                 // (4,512,512,4) interleaved A0,A1,A2,b = 16 MB

    k_f1<<<dim3(16 * 32 * NB), dim3(256), 0, stream>>>(y, x, ab);   // 2048 blocks
    k_f2<<<dim3(8 * 32 * NB), dim3(256), 0, stream>>>(ab, x, out);  // 1024 blocks
}